// Round 2
// baseline (661.667 us; speedup 1.0000x reference)
//
#include <hip/hip_runtime.h>
#include <hip/hip_bf16.h>

typedef unsigned short u16t;

namespace {

constexpr int kB = 16, kD = 64, kN = 200, kT = 48, kH = 8;
constexpr float kEps = 1e-5f;

__device__ __forceinline__ float bf2f(unsigned int u) {
  union { unsigned int i; float f; } v; v.i = u << 16; return v.f;
}
__device__ __forceinline__ float bf2f_hi(unsigned int u) {
  union { unsigned int i; float f; } v; v.i = u & 0xffff0000u; return v.f;
}
__device__ __forceinline__ void unpack8(const int4 p, float* o) {
  o[0] = bf2f((unsigned int)p.x); o[1] = bf2f_hi((unsigned int)p.x);
  o[2] = bf2f((unsigned int)p.y); o[3] = bf2f_hi((unsigned int)p.y);
  o[4] = bf2f((unsigned int)p.z); o[5] = bf2f_hi((unsigned int)p.z);
  o[6] = bf2f((unsigned int)p.w); o[7] = bf2f_hi((unsigned int)p.w);
}

template<bool BF>
__device__ __forceinline__ float ldg1(const void* p, size_t i) {
  if constexpr (BF) return bf2f(((const u16t*)p)[i]);
  else return ((const float*)p)[i];
}
template<bool BF>
__device__ __forceinline__ void ldg8(const void* p, size_t i, float* o) {
  if constexpr (BF) {
    const int4 v = *(const int4*)((const u16t*)p + i);
    unpack8(v, o);
  } else {
    const float4* q = (const float4*)((const float*)p + i);
    const float4 a = q[0], b = q[1];
    o[0]=a.x; o[1]=a.y; o[2]=a.z; o[3]=a.w; o[4]=b.x; o[5]=b.y; o[6]=b.z; o[7]=b.w;
  }
}
template<bool BF>
__device__ __forceinline__ void stg1(void* p, size_t i, float v) {
  if constexpr (BF) ((__hip_bfloat16*)p)[i] = __float2bfloat16(v);
  else ((float*)p)[i] = v;
}

// ---- dtype detector: bf16-decode of true bf16 is small; of fp32 bits is huge ----
__global__ void detect_dtype(const u16t* __restrict__ x, int* __restrict__ flag) {
  float mx = 0.f;
  for (int i = threadIdx.x; i < 4096; i += 64) {
    float v = fabsf(bf2f(x[i]));
    if (!(v < 1e30f)) v = 1e30f;          // NaN/inf bit patterns count as huge
    mx = fmaxf(mx, v);
  }
  #pragma unroll
  for (int off = 32; off > 0; off >>= 1) mx = fmaxf(mx, __shfl_xor(mx, off, 64));
  if (threadIdx.x == 0) *flag = (mx < 100.f) ? 1 : 0;   // 1 = bf16, 0 = fp32
}

// ---------------- Kernel 1: temporal attention + LN + residual -> h (into d_out) ----------------
template<bool BF>
__global__ __launch_bounds__(256, 2) void k1_temporal(
    const void* __restrict__ x,
    const void* __restrict__ Wq, const void* __restrict__ bq,
    const void* __restrict__ Wk, const void* __restrict__ bk,
    const void* __restrict__ W1, const void* __restrict__ b1,
    const void* __restrict__ W2, const void* __restrict__ b2,
    const void* __restrict__ g0, const void* __restrict__ beta0,
    void* __restrict__ hout, const int* __restrict__ flag)
{
  if (*flag != (BF ? 1 : 0)) return;

  __shared__ __align__(16) float lds[15616];
  float* xs = lds;              // [64][52]  col = t+1, halo zeros at cols 0,49,50,51
  float* qs = lds + 3328;       // [64][48]  (later reused for tout)
  float* ks = lds + 6400;       // [64][48]
  float* vs = lds + 9472;       // [64][48]  (later reused for LN reductions)
  float* os = lds + 12544;      // [64][48]  attention output (pre-W2)

  const int tid = threadIdx.x;
  const int b = blockIdx.x / kN, n = blockIdx.x % kN;

  // ---- stage x[b,:,n,:] into LDS fp32 ----
  for (int idx = tid; idx < kD * 6; idx += 256) {
    const int d = idx / 6, j = idx % 6;
    const size_t xi = (size_t)b * (kD*kN*kT) + (size_t)d * (kN*kT) + (size_t)n * kT + j * 8;
    float tmp[8]; ldg8<BF>(x, xi, tmp);
    float* dst = xs + d * 52 + 1 + j * 8;
    #pragma unroll
    for (int e = 0; e < 8; ++e) dst[e] = tmp[e];
  }
  if (tid < 64) { xs[tid*52] = 0.f; xs[tid*52+49] = 0.f; xs[tid*52+50] = 0.f; xs[tid*52+51] = 0.f; }
  __syncthreads();

  // ---- fused conv1x3 q, conv1x3 k, v = x^T W1^T + b1 ----
  {
    const int dq = tid >> 2, t0 = (tid & 3) * 12;
    float aq[12], ak[12], av[12];
    {
      const float vq = ldg1<BF>(bq, dq), vk = ldg1<BF>(bk, dq), vv = ldg1<BF>(b1, dq);
      #pragma unroll
      for (int j = 0; j < 12; ++j) { aq[j] = vq; ak[j] = vk; av[j] = vv; }
    }
    for (int din = 0; din < 64; ++din) {
      union { float4 v4[4]; float f[16]; } X;
      const float4* xr = (const float4*)(xs + din * 52 + t0);
      X.v4[0] = xr[0]; X.v4[1] = xr[1]; X.v4[2] = xr[2]; X.v4[3] = xr[3];
      const size_t wbase = (size_t)dq * 192 + din * 3;
      const float wq0 = ldg1<BF>(Wq, wbase), wq1 = ldg1<BF>(Wq, wbase+1), wq2 = ldg1<BF>(Wq, wbase+2);
      const float wk0 = ldg1<BF>(Wk, wbase), wk1 = ldg1<BF>(Wk, wbase+1), wk2 = ldg1<BF>(Wk, wbase+2);
      const float w1v = ldg1<BF>(W1, (size_t)dq * 64 + din);
      #pragma unroll
      for (int j = 0; j < 12; ++j) {
        aq[j] += X.f[j]*wq0 + X.f[j+1]*wq1 + X.f[j+2]*wq2;
        ak[j] += X.f[j]*wk0 + X.f[j+1]*wk1 + X.f[j+2]*wk2;
        av[j] += X.f[j+1]*w1v;
      }
    }
    float* qd = qs + dq*48 + t0;
    float* kd = ks + dq*48 + t0;
    float* vd = vs + dq*48 + t0;
    #pragma unroll
    for (int j = 0; j < 12; ++j) { qd[j] = aq[j]; kd[j] = ak[j]; vd[j] = av[j]; }
  }
  __syncthreads();

  // ---- per (h,t): scores, softmax, P@V ----
  for (int pair = tid; pair < kH * kT; pair += 256) {
    const int hh = pair / kT, t = pair % kT;
    const int rb = hh * 8;
    float qv[8];
    #pragma unroll
    for (int dk = 0; dk < 8; ++dk) qv[dk] = qs[(rb+dk)*48 + t];
    float sc[48];
    #pragma unroll
    for (int s = 0; s < 48; ++s) sc[s] = 0.f;
    #pragma unroll
    for (int dk = 0; dk < 8; ++dk) {
      const float4* kr = (const float4*)(ks + (rb+dk)*48);
      const float q = qv[dk];
      #pragma unroll
      for (int s4 = 0; s4 < 12; ++s4) {
        const float4 k4 = kr[s4];
        sc[s4*4+0] += q*k4.x; sc[s4*4+1] += q*k4.y;
        sc[s4*4+2] += q*k4.z; sc[s4*4+3] += q*k4.w;
      }
    }
    float mx = -3.4e38f;
    #pragma unroll
    for (int s = 0; s < 48; ++s) { sc[s] *= 0.35355339059327373f; mx = fmaxf(mx, sc[s]); }
    float esum = 0.f;
    #pragma unroll
    for (int s = 0; s < 48; ++s) { sc[s] = __expf(fminf(sc[s] - mx, 0.f)); esum += sc[s]; }
    const float inv = 1.f / esum;
    #pragma unroll
    for (int dk = 0; dk < 8; ++dk) {
      const float4* vr = (const float4*)(vs + (rb+dk)*48);
      float a = 0.f;
      #pragma unroll
      for (int s4 = 0; s4 < 12; ++s4) {
        const float4 v4 = vr[s4];
        a += sc[s4*4+0]*v4.x + sc[s4*4+1]*v4.y + sc[s4*4+2]*v4.z + sc[s4*4+3]*v4.w;
      }
      os[(rb+dk)*48 + t] = a * inv;
    }
  }
  __syncthreads();

  // ---- W2 projection -> qs (tout) ----
  {
    const int dq = tid >> 2, t0 = (tid & 3) * 12;
    float ao[12];
    const float b2v = ldg1<BF>(b2, dq);
    #pragma unroll
    for (int j = 0; j < 12; ++j) ao[j] = b2v;
    for (int din = 0; din < 64; ++din) {
      union { float4 v4[3]; float f[12]; } O;
      const float4* orow = (const float4*)(os + din*48 + t0);
      O.v4[0] = orow[0]; O.v4[1] = orow[1]; O.v4[2] = orow[2];
      const float w = ldg1<BF>(W2, (size_t)dq * 64 + din);
      #pragma unroll
      for (int j = 0; j < 12; ++j) ao[j] += O.f[j] * w;
    }
    float* td = qs + dq*48 + t0;
    #pragma unroll
    for (int j = 0; j < 12; ++j) td[j] = ao[j];
  }
  __syncthreads();

  // ---- LayerNorm over D + residual, write h ----
  float* redm = vs;         // [48][4]
  float* redv = vs + 192;   // [48][4]
  float* mrs  = vs + 384;   // [48]
  float* rrs  = vs + 432;   // [48]
  if (tid < 192) {
    const int t = tid >> 2, grp = tid & 3;
    float sm = 0.f, sq = 0.f;
    #pragma unroll
    for (int i = 0; i < 16; ++i) {
      const float v = qs[(grp*16+i)*48 + t];
      sm += v; sq += v*v;
    }
    redm[t*4+grp] = sm; redv[t*4+grp] = sq;
  }
  __syncthreads();
  if (tid < 48) {
    const int t = tid;
    const float sm = redm[t*4] + redm[t*4+1] + redm[t*4+2] + redm[t*4+3];
    const float sq = redv[t*4] + redv[t*4+1] + redv[t*4+2] + redv[t*4+3];
    const float mean = sm * (1.f/64.f);
    const float var = sq * (1.f/64.f) - mean*mean;
    mrs[t] = mean; rrs[t] = rsqrtf(fmaxf(var, 0.f) + kEps);
  }
  __syncthreads();
  if (tid < 192) {
    const int t = tid >> 2, grp = tid & 3;
    const float mean = mrs[t], rs = rrs[t];
    const size_t base = (((size_t)b*kN + n)*kT + t)*kD;
    #pragma unroll
    for (int i = 0; i < 16; ++i) {
      const int d = grp*16 + i;
      const float tout = qs[d*48 + t];
      const float xv = xs[d*52 + t + 1];
      const float hval = xv + (tout - mean)*rs*ldg1<BF>(g0, d) + ldg1<BF>(beta0, d);
      stg1<BF>(hout, base + d, hval);
    }
  }
}

// ---------------- Kernel 2: spatial GCN + LN + residual, in-place on d_out ----------------
template<bool BF>
__global__ __launch_bounds__(256, 2) void k2_spatial(
    void* __restrict__ hio, const void* __restrict__ adj,
    const void* __restrict__ Theta, const void* __restrict__ g1,
    const void* __restrict__ beta1, const int* __restrict__ flag)
{
  if (*flag != (BF ? 1 : 0)) return;

  __shared__ __align__(16) float lds[12800 + 4*832];
  float* hsb = lds;                         // 200x64 fp32, chunk-rotation swizzle
  const int tid = threadIdx.x;
  const int wave = tid >> 6, lane = tid & 63;
  float* wb = lds + 12800 + wave * 832;     // per-wave scratch: 4 rows x 208

  const int b = blockIdx.x / kT, t = blockIdx.x % kT;

  // Theta row cache in registers: lane d holds Theta[d][0..63]
  float th[64];
  #pragma unroll
  for (int j = 0; j < 8; ++j) ldg8<BF>(Theta, (size_t)lane*64 + j*8, th + j*8);
  const float g1f  = ldg1<BF>(g1, lane);
  const float be1f = ldg1<BF>(beta1, lane);

  const float4* hs4 = (const float4*)hsb;
  float4* hs4w = (float4*)hsb;
  // load h(b,:,t,:) with chunk-rotation swizzle: chunk c of row n -> float4 slot n*16 + ((c+n)&15)
  for (int idx = tid; idx < kN * 8; idx += 256) {
    const int n = idx >> 3, j = idx & 7;
    float tmp[8]; ldg8<BF>(hio, (((size_t)b*kN + n)*kT + t)*kD + j*8, tmp);
    const int c0 = 2*j;
    hs4w[n*16 + ((c0 + n) & 15)]     = make_float4(tmp[0], tmp[1], tmp[2], tmp[3]);
    hs4w[n*16 + ((c0 + 1 + n) & 15)] = make_float4(tmp[4], tmp[5], tmp[6], tmp[7]);
  }
  __syncthreads();

  for (int g = wave; g < 50; g += 4) {
    const int n0 = g * 4;
    float acc[4][4];                       // [m-rep][row]
    #pragma unroll
    for (int rp = 0; rp < 4; ++rp)
      #pragma unroll
      for (int r = 0; r < 4; ++r) acc[rp][r] = 0.f;
    int mm[4]; bool act[4];
    #pragma unroll
    for (int rp = 0; rp < 4; ++rp) {
      const int m = rp*64 + lane;
      act[rp] = (m < kN); mm[rp] = act[rp] ? m : (kN - 1);
    }
    for (int c = 0; c < 16; ++c) {
      float4 bb[4];
      #pragma unroll
      for (int r = 0; r < 4; ++r) bb[r] = hs4[(n0+r)*16 + ((c + n0 + r) & 15)];
      #pragma unroll
      for (int rp = 0; rp < 4; ++rp) {
        const float4 vm = hs4[mm[rp]*16 + ((c + mm[rp]) & 15)];
        #pragma unroll
        for (int r = 0; r < 4; ++r)
          acc[rp][r] += vm.x*bb[r].x + vm.y*bb[r].y + vm.z*bb[r].z + vm.w*bb[r].w;
      }
    }
    // softmax per row + adjacency weighting -> wb
    #pragma unroll
    for (int r = 0; r < 4; ++r) {
      float mx = -3.4e38f;
      #pragma unroll
      for (int rp = 0; rp < 4; ++rp) {
        const float v = act[rp] ? acc[rp][r]*0.125f : -3.4e38f;   // /sqrt(64)
        acc[rp][r] = v; mx = fmaxf(mx, v);
      }
      #pragma unroll
      for (int off = 32; off > 0; off >>= 1) mx = fmaxf(mx, __shfl_xor(mx, off, 64));
      float es[4]; float lsum = 0.f;
      #pragma unroll
      for (int rp = 0; rp < 4; ++rp) {
        es[rp] = act[rp] ? __expf(fminf(acc[rp][r] - mx, 0.f)) : 0.f;
        lsum += es[rp];
      }
      #pragma unroll
      for (int off = 32; off > 0; off >>= 1) lsum += __shfl_xor(lsum, off, 64);
      const float scale = 0.125f / lsum;     // softmax / sqrt(D)
      #pragma unroll
      for (int rp = 0; rp < 4; ++rp) if (act[rp]) {
        const float adjv = ldg1<BF>(adj, (size_t)(n0+r)*kN + rp*64 + lane);
        wb[r*208 + rp*64 + lane] = es[rp]*scale*adjv;
      }
    }
    // agg[r][:] = sum_m w[r][m]*h[m][:]; lane = (m-quarter, d-chunk)
    const int cc = lane & 15, rp2 = lane >> 4;
    float4 ag[4];
    #pragma unroll
    for (int r = 0; r < 4; ++r) ag[r] = make_float4(0.f,0.f,0.f,0.f);
    for (int m = rp2*50; m < rp2*50 + 50; ++m) {
      const float4 hv = hs4[m*16 + ((cc + m) & 15)];
      #pragma unroll
      for (int r = 0; r < 4; ++r) {
        const float w = wb[r*208 + m];
        ag[r].x += w*hv.x; ag[r].y += w*hv.y; ag[r].z += w*hv.z; ag[r].w += w*hv.w;
      }
    }
    #pragma unroll
    for (int r = 0; r < 4; ++r) {
      ag[r].x += __shfl_xor(ag[r].x, 16, 64); ag[r].y += __shfl_xor(ag[r].y, 16, 64);
      ag[r].z += __shfl_xor(ag[r].z, 16, 64); ag[r].w += __shfl_xor(ag[r].w, 16, 64);
      ag[r].x += __shfl_xor(ag[r].x, 32, 64); ag[r].y += __shfl_xor(ag[r].y, 32, 64);
      ag[r].z += __shfl_xor(ag[r].z, 32, 64); ag[r].w += __shfl_xor(ag[r].w, 32, 64);
    }
    if (lane < 16) {                         // overlay agg rows onto consumed weights
      #pragma unroll
      for (int r = 0; r < 4; ++r) *(float4*)(wb + r*208 + cc*4) = ag[r];
    }
    // Theta proj + relu + LN + residual; lane = d
    #pragma unroll
    for (int r = 0; r < 4; ++r) {
      float s = 0.f;
      #pragma unroll
      for (int c2 = 0; c2 < 16; ++c2) {
        const float4 a4 = *(const float4*)(wb + r*208 + c2*4);
        s += a4.x*th[c2*4+0] + a4.y*th[c2*4+1] + a4.z*th[c2*4+2] + a4.w*th[c2*4+3];
      }
      s = fmaxf(s, 0.f);
      float sm = s, sq = s*s;
      #pragma unroll
      for (int off = 32; off > 0; off >>= 1) {
        sm += __shfl_xor(sm, off, 64);
        sq += __shfl_xor(sq, off, 64);
      }
      const float mean = sm * (1.f/64.f);
      const float var = sq * (1.f/64.f) - mean*mean;
      const float nrm = (s - mean)*rsqrtf(fmaxf(var, 0.f) + kEps)*g1f + be1f;
      const float hval = hsb[(n0+r)*64 + ((((lane>>2) + n0 + r) & 15) << 2) + (lane & 3)];
      stg1<BF>(hio, (((size_t)b*kN + n0 + r)*kT + t)*kD + lane, hval + nrm);
    }
  }
}

} // namespace

extern "C" void kernel_launch(void* const* d_in, const int* in_sizes, int n_in,
                              void* d_out, int out_size, void* d_ws, size_t ws_size,
                              hipStream_t stream) {
  const void* x     = d_in[0];
  const void* adj   = d_in[1];
  const void* Wq    = d_in[2];
  const void* bq    = d_in[3];
  const void* Wk    = d_in[4];
  const void* bk    = d_in[5];
  const void* W1    = d_in[6];
  const void* b1    = d_in[7];
  const void* W2    = d_in[8];
  const void* b2    = d_in[9];
  const void* Theta = d_in[10];
  const void* g0    = d_in[11];
  const void* beta0 = d_in[12];
  const void* g1    = d_in[13];
  const void* beta1 = d_in[14];

  int* flag = (int*)d_ws;

  detect_dtype<<<dim3(1), dim3(64), 0, stream>>>((const u16t*)x, flag);

  // h staged in-place through d_out; wrong-dtype variants exit immediately.
  k1_temporal<true ><<<dim3(kB*kN), dim3(256), 0, stream>>>(
      x, Wq, bq, Wk, bk, W1, b1, W2, b2, g0, beta0, d_out, flag);
  k1_temporal<false><<<dim3(kB*kN), dim3(256), 0, stream>>>(
      x, Wq, bq, Wk, bk, W1, b1, W2, b2, g0, beta0, d_out, flag);
  k2_spatial<true ><<<dim3(kB*kT), dim3(256), 0, stream>>>(
      d_out, adj, Theta, g1, beta1, flag);
  k2_spatial<false><<<dim3(kB*kT), dim3(256), 0, stream>>>(
      d_out, adj, Theta, g1, beta1, flag);
}

// Round 6
// 649.965 us; speedup vs baseline: 1.0180x; 1.0180x over previous
//
#include <hip/hip_runtime.h>
#include <hip/hip_bf16.h>

typedef unsigned short u16t;

namespace {

constexpr int kB = 16, kD = 64, kN = 200, kT = 48, kH = 8;
constexpr float kEps = 1e-5f;

typedef __attribute__((ext_vector_type(8))) __bf16 bf16x8;
typedef __attribute__((ext_vector_type(4))) float f32x4;
union B8 { int4 i; bf16x8 v; u16t u[8]; };

__device__ __forceinline__ u16t f2bfu(float f) {
  union { __hip_bfloat16 h; u16t u; } c; c.h = __float2bfloat16(f); return c.u;
}

// ---------------- Kernel 1: temporal attention + LN + residual -> h (into d_out), fp32 ----------------
__global__ __launch_bounds__(256, 2) void k1_temporal(
    const float* __restrict__ x,
    const float* __restrict__ Wq, const float* __restrict__ bq,
    const float* __restrict__ Wk, const float* __restrict__ bk,
    const float* __restrict__ W1, const float* __restrict__ b1,
    const float* __restrict__ W2, const float* __restrict__ b2,
    const float* __restrict__ g0, const float* __restrict__ beta0,
    float* __restrict__ hout)
{
  __shared__ __align__(16) float lds[15616];
  float* xs = lds;              // [64][52]  col = t+1, halo zeros at cols 0,49,50,51
  float* qs = lds + 3328;       // [64][48]  (later reused for tout)
  float* ks = lds + 6400;       // [64][48]
  float* vs = lds + 9472;       // [64][48]  (later reused for LN reductions)
  float* os = lds + 12544;      // [64][48]  attention output (pre-W2)

  const int tid = threadIdx.x;
  const int b = blockIdx.x / kN, n = blockIdx.x % kN;

  // ---- stage x[b,:,n,:] into LDS fp32 ----
  for (int idx = tid; idx < kD * 6; idx += 256) {
    const int d = idx / 6, j = idx % 6;
    const size_t xi = (size_t)b * (kD*kN*kT) + (size_t)d * (kN*kT) + (size_t)n * kT + j * 8;
    const float4* q = (const float4*)(x + xi);
    const float4 p0 = q[0], p1 = q[1];
    float* dst = xs + d * 52 + 1 + j * 8;
    dst[0]=p0.x; dst[1]=p0.y; dst[2]=p0.z; dst[3]=p0.w;
    dst[4]=p1.x; dst[5]=p1.y; dst[6]=p1.z; dst[7]=p1.w;
  }
  if (tid < 64) { xs[tid*52] = 0.f; xs[tid*52+49] = 0.f; xs[tid*52+50] = 0.f; xs[tid*52+51] = 0.f; }
  __syncthreads();

  // ---- fused conv1x3 q, conv1x3 k, v = x^T W1^T + b1 ----
  {
    const int dq = tid >> 2, t0 = (tid & 3) * 12;
    float aq[12], ak[12], av[12];
    {
      const float vq = bq[dq], vk = bk[dq], vv = b1[dq];
      #pragma unroll
      for (int j = 0; j < 12; ++j) { aq[j] = vq; ak[j] = vk; av[j] = vv; }
    }
    for (int din = 0; din < 64; ++din) {
      union { float4 v4[4]; float f[16]; } X;
      const float4* xr = (const float4*)(xs + din * 52 + t0);
      X.v4[0] = xr[0]; X.v4[1] = xr[1]; X.v4[2] = xr[2]; X.v4[3] = xr[3];
      const size_t wbase = (size_t)dq * 192 + din * 3;
      const float wq0 = Wq[wbase], wq1 = Wq[wbase+1], wq2 = Wq[wbase+2];
      const float wk0 = Wk[wbase], wk1 = Wk[wbase+1], wk2 = Wk[wbase+2];
      const float w1v = W1[(size_t)dq * 64 + din];
      #pragma unroll
      for (int j = 0; j < 12; ++j) {
        aq[j] += X.f[j]*wq0 + X.f[j+1]*wq1 + X.f[j+2]*wq2;
        ak[j] += X.f[j]*wk0 + X.f[j+1]*wk1 + X.f[j+2]*wk2;
        av[j] += X.f[j+1]*w1v;
      }
    }
    float* qd = qs + dq*48 + t0;
    float* kd = ks + dq*48 + t0;
    float* vd = vs + dq*48 + t0;
    #pragma unroll
    for (int j = 0; j < 12; ++j) { qd[j] = aq[j]; kd[j] = ak[j]; vd[j] = av[j]; }
  }
  __syncthreads();

  // ---- per (h,t): scores, softmax, P@V ----
  for (int pair = tid; pair < kH * kT; pair += 256) {
    const int hh = pair / kT, t = pair % kT;
    const int rb = hh * 8;
    float qv[8];
    #pragma unroll
    for (int dk = 0; dk < 8; ++dk) qv[dk] = qs[(rb+dk)*48 + t];
    float sc[48];
    #pragma unroll
    for (int s = 0; s < 48; ++s) sc[s] = 0.f;
    #pragma unroll
    for (int dk = 0; dk < 8; ++dk) {
      const float4* kr = (const float4*)(ks + (rb+dk)*48);
      const float q = qv[dk];
      #pragma unroll
      for (int s4 = 0; s4 < 12; ++s4) {
        const float4 k4 = kr[s4];
        sc[s4*4+0] += q*k4.x; sc[s4*4+1] += q*k4.y;
        sc[s4*4+2] += q*k4.z; sc[s4*4+3] += q*k4.w;
      }
    }
    float mx = -3.4e38f;
    #pragma unroll
    for (int s = 0; s < 48; ++s) { sc[s] *= 0.35355339059327373f; mx = fmaxf(mx, sc[s]); }
    float esum = 0.f;
    #pragma unroll
    for (int s = 0; s < 48; ++s) { sc[s] = __expf(fminf(sc[s] - mx, 0.f)); esum += sc[s]; }
    const float inv = 1.f / esum;
    #pragma unroll
    for (int dk = 0; dk < 8; ++dk) {
      const float4* vr = (const float4*)(vs + (rb+dk)*48);
      float a = 0.f;
      #pragma unroll
      for (int s4 = 0; s4 < 12; ++s4) {
        const float4 v4 = vr[s4];
        a += sc[s4*4+0]*v4.x + sc[s4*4+1]*v4.y + sc[s4*4+2]*v4.z + sc[s4*4+3]*v4.w;
      }
      os[(rb+dk)*48 + t] = a * inv;
    }
  }
  __syncthreads();

  // ---- W2 projection -> qs (tout) ----
  {
    const int dq = tid >> 2, t0 = (tid & 3) * 12;
    float ao[12];
    const float b2v = b2[dq];
    #pragma unroll
    for (int j = 0; j < 12; ++j) ao[j] = b2v;
    for (int din = 0; din < 64; ++din) {
      union { float4 v4[3]; float f[12]; } O;
      const float4* orow = (const float4*)(os + din*48 + t0);
      O.v4[0] = orow[0]; O.v4[1] = orow[1]; O.v4[2] = orow[2];
      const float w = W2[(size_t)dq * 64 + din];
      #pragma unroll
      for (int j = 0; j < 12; ++j) ao[j] += O.f[j] * w;
    }
    float* td = qs + dq*48 + t0;
    #pragma unroll
    for (int j = 0; j < 12; ++j) td[j] = ao[j];
  }
  __syncthreads();

  // ---- LayerNorm over D + residual, write h ----
  float* redm = vs;         // [48][4]
  float* redv = vs + 192;   // [48][4]
  float* mrs  = vs + 384;   // [48]
  float* rrs  = vs + 432;   // [48]
  if (tid < 192) {
    const int t = tid >> 2, grp = tid & 3;
    float sm = 0.f, sq = 0.f;
    #pragma unroll
    for (int i = 0; i < 16; ++i) {
      const float v = qs[(grp*16+i)*48 + t];
      sm += v; sq += v*v;
    }
    redm[t*4+grp] = sm; redv[t*4+grp] = sq;
  }
  __syncthreads();
  if (tid < 48) {
    const int t = tid;
    const float sm = redm[t*4] + redm[t*4+1] + redm[t*4+2] + redm[t*4+3];
    const float sq = redv[t*4] + redv[t*4+1] + redv[t*4+2] + redv[t*4+3];
    const float mean = sm * (1.f/64.f);
    const float var = sq * (1.f/64.f) - mean*mean;
    mrs[t] = mean; rrs[t] = rsqrtf(fmaxf(var, 0.f) + kEps);
  }
  __syncthreads();
  if (tid < 192) {
    const int t = tid >> 2, grp = tid & 3;
    const float mean = mrs[t], rs = rrs[t];
    const size_t base = (((size_t)b*kN + n)*kT + t)*kD;
    #pragma unroll
    for (int i = 0; i < 16; ++i) {
      const int d = grp*16 + i;
      const float tout = qs[d*48 + t];
      const float xv = xs[d*52 + t + 1];
      hout[base + d] = xv + (tout - mean)*rs*g0[d] + beta0[d];
    }
  }
}

// ---------------- Kernel 2: spatial GCN + LN + residual (fp32, R2-proven), in-place ----------------
__global__ __launch_bounds__(256, 2) void k2_spatial(
    float* __restrict__ hio, const float* __restrict__ adj,
    const float* __restrict__ Theta, const float* __restrict__ g1,
    const float* __restrict__ beta1)
{
  __shared__ __align__(16) float lds[12800 + 4*832];
  float* hsb = lds;                         // 200x64 fp32, chunk-rotation swizzle
  const int tid = threadIdx.x;
  const int wave = tid >> 6, lane = tid & 63;
  float* wb = lds + 12800 + wave * 832;     // per-wave scratch: 4 rows x 208

  const int b = blockIdx.x / kT, t = blockIdx.x % kT;

  float th[64];
  #pragma unroll
  for (int j = 0; j < 8; ++j) {
    const float4* tp = (const float4*)(Theta + (size_t)lane*64 + j*8);
    const float4 a = tp[0], c = tp[1];
    th[j*8+0]=a.x; th[j*8+1]=a.y; th[j*8+2]=a.z; th[j*8+3]=a.w;
    th[j*8+4]=c.x; th[j*8+5]=c.y; th[j*8+6]=c.z; th[j*8+7]=c.w;
  }
  const float g1f  = g1[lane];
  const float be1f = beta1[lane];

  const float4* hs4 = (const float4*)hsb;
  float4* hs4w = (float4*)hsb;
  for (int idx = tid; idx < kN * 8; idx += 256) {
    const int n = idx >> 3, j = idx & 7;
    const float4* q = (const float4*)(hio + (((size_t)b*kN + n)*kT + t)*kD + j*8);
    const float4 p0 = q[0], p1 = q[1];
    const int c0 = 2*j;
    hs4w[n*16 + ((c0 + n) & 15)]     = p0;
    hs4w[n*16 + ((c0 + 1 + n) & 15)] = p1;
  }
  __syncthreads();

  for (int g = wave; g < 50; g += 4) {
    const int n0 = g * 4;
    float acc[4][4];                       // [m-rep][row]
    #pragma unroll
    for (int rp = 0; rp < 4; ++rp)
      #pragma unroll
      for (int r = 0; r < 4; ++r) acc[rp][r] = 0.f;
    int mm[4]; bool act[4];
    #pragma unroll
    for (int rp = 0; rp < 4; ++rp) {
      const int m = rp*64 + lane;
      act[rp] = (m < kN); mm[rp] = act[rp] ? m : (kN - 1);
    }
    for (int c = 0; c < 16; ++c) {
      float4 bb[4];
      #pragma unroll
      for (int r = 0; r < 4; ++r) bb[r] = hs4[(n0+r)*16 + ((c + n0 + r) & 15)];
      #pragma unroll
      for (int rp = 0; rp < 4; ++rp) {
        const float4 vm = hs4[mm[rp]*16 + ((c + mm[rp]) & 15)];
        #pragma unroll
        for (int r = 0; r < 4; ++r)
          acc[rp][r] += vm.x*bb[r].x + vm.y*bb[r].y + vm.z*bb[r].z + vm.w*bb[r].w;
      }
    }
    #pragma unroll
    for (int r = 0; r < 4; ++r) {
      float mx = -3.4e38f;
      #pragma unroll
      for (int rp = 0; rp < 4; ++rp) {
        const float v = act[rp] ? acc[rp][r]*0.125f : -3.4e38f;
        acc[rp][r] = v; mx = fmaxf(mx, v);
      }
      #pragma unroll
      for (int off = 32; off > 0; off >>= 1) mx = fmaxf(mx, __shfl_xor(mx, off, 64));
      float es[4]; float lsum = 0.f;
      #pragma unroll
      for (int rp = 0; rp < 4; ++rp) {
        es[rp] = act[rp] ? __expf(fminf(acc[rp][r] - mx, 0.f)) : 0.f;
        lsum += es[rp];
      }
      #pragma unroll
      for (int off = 32; off > 0; off >>= 1) lsum += __shfl_xor(lsum, off, 64);
      const float scale = 0.125f / lsum;
      #pragma unroll
      for (int rp = 0; rp < 4; ++rp) if (act[rp]) {
        const float adjv = adj[(size_t)(n0+r)*kN + rp*64 + lane];
        wb[r*208 + rp*64 + lane] = es[rp]*scale*adjv;
      }
    }
    const int cc = lane & 15, rp2 = lane >> 4;
    float4 ag[4];
    #pragma unroll
    for (int r = 0; r < 4; ++r) ag[r] = make_float4(0.f,0.f,0.f,0.f);
    for (int m = rp2*50; m < rp2*50 + 50; ++m) {
      const float4 hv = hs4[m*16 + ((cc + m) & 15)];
      #pragma unroll
      for (int r = 0; r < 4; ++r) {
        const float w = wb[r*208 + m];
        ag[r].x += w*hv.x; ag[r].y += w*hv.y; ag[r].z += w*hv.z; ag[r].w += w*hv.w;
      }
    }
    #pragma unroll
    for (int r = 0; r < 4; ++r) {
      ag[r].x += __shfl_xor(ag[r].x, 16, 64); ag[r].y += __shfl_xor(ag[r].y, 16, 64);
      ag[r].z += __shfl_xor(ag[r].z, 16, 64); ag[r].w += __shfl_xor(ag[r].w, 16, 64);
      ag[r].x += __shfl_xor(ag[r].x, 32, 64); ag[r].y += __shfl_xor(ag[r].y, 32, 64);
      ag[r].z += __shfl_xor(ag[r].z, 32, 64); ag[r].w += __shfl_xor(ag[r].w, 32, 64);
    }
    if (lane < 16) {
      #pragma unroll
      for (int r = 0; r < 4; ++r) *(float4*)(wb + r*208 + cc*4) = ag[r];
    }
    #pragma unroll
    for (int r = 0; r < 4; ++r) {
      float s = 0.f;
      #pragma unroll
      for (int c2 = 0; c2 < 16; ++c2) {
        const float4 a4 = *(const float4*)(wb + r*208 + c2*4);
        s += a4.x*th[c2*4+0] + a4.y*th[c2*4+1] + a4.z*th[c2*4+2] + a4.w*th[c2*4+3];
      }
      s = fmaxf(s, 0.f);
      float sm = s, sq = s*s;
      #pragma unroll
      for (int off = 32; off > 0; off >>= 1) {
        sm += __shfl_xor(sm, off, 64);
        sq += __shfl_xor(sq, off, 64);
      }
      const float mean = sm * (1.f/64.f);
      const float var = sq * (1.f/64.f) - mean*mean;
      const float nrm = (s - mean)*rsqrtf(fmaxf(var, 0.f) + kEps)*g1f + be1f;
      const float hval = hsb[(n0+r)*64 + ((((lane>>2) + n0 + r) & 15) << 2) + (lane & 3)];
      hio[(((size_t)b*kN + n0 + r)*kT + t)*kD + lane] = hval + nrm;
    }
  }
}

// ---------------- Probe: MFMA fragment semantics (registers only, writes d_ws only) ----------------
// Duration side channel: H0 (m89 layout) ok -> ~us (invisible); C/D-transposed -> ~+1ms;
// neither -> ~+3ms on dur_us.
__global__ void probe_frag(float* __restrict__ ws) {
  const int lane = threadIdx.x & 63;
  const int c15 = lane & 15, quad = lane >> 4;
  B8 a, bt;
  #pragma unroll
  for (int j = 0; j < 8; ++j) {
    const int k = quad*8 + j;
    a.u[j]  = f2bfu((float)(((c15*7 + k) % 13) - 6));
    bt.u[j] = f2bfu((float)(((c15*11 + k*5) % 9) - 4));
  }
  f32x4 d = {0.f, 0.f, 0.f, 0.f};
  d = __builtin_amdgcn_mfma_f32_16x16x32_bf16(a.v, bt.v, d, 0, 0, 0);
  bool h0 = true, h1 = true;
  #pragma unroll
  for (int r = 0; r < 4; ++r) {
    const int row = quad*4 + r;
    float s0 = 0.f, s1 = 0.f;
    for (int k = 0; k < 32; ++k) {
      const float A_row = (float)(((row*7 + k) % 13) - 6);
      const float A_c15 = (float)(((c15*7 + k) % 13) - 6);
      const float B_c15 = (float)(((c15*11 + k*5) % 9) - 4);
      const float B_row = (float)(((row*11 + k*5) % 9) - 4);
      s0 += A_row * B_c15;
      s1 += A_c15 * B_row;
    }
    if (d[r] != s0) h0 = false;
    if (d[r] != s1) h1 = false;
  }
  h0 = __all(h0); h1 = __all(h1);
  const long spin = h0 ? 0 : (h1 ? 600000 : 1800000);
  float v = d[0] + d[1] + d[2] + d[3];
  for (long i = 0; i < spin; ++i) v = fmaf(v, 1.0000001f, 1e-9f);
  ws[lane] = v;
}

} // namespace

extern "C" void kernel_launch(void* const* d_in, const int* in_sizes, int n_in,
                              void* d_out, int out_size, void* d_ws, size_t ws_size,
                              hipStream_t stream) {
  const float* x     = (const float*)d_in[0];
  const float* adj   = (const float*)d_in[1];
  const float* Wq    = (const float*)d_in[2];
  const float* bq    = (const float*)d_in[3];
  const float* Wk    = (const float*)d_in[4];
  const float* bk    = (const float*)d_in[5];
  const float* W1    = (const float*)d_in[6];
  const float* b1    = (const float*)d_in[7];
  const float* W2    = (const float*)d_in[8];
  const float* b2    = (const float*)d_in[9];
  const float* Theta = (const float*)d_in[10];
  const float* g0    = (const float*)d_in[11];
  const float* beta0 = (const float*)d_in[12];
  const float* g1    = (const float*)d_in[13];
  const float* beta1 = (const float*)d_in[14];

  float* hbuf = (float*)d_out;   // h staged in-place through d_out (fp32)

  k1_temporal<<<dim3(kB*kN), dim3(256), 0, stream>>>(
      x, Wq, bq, Wk, bk, W1, b1, W2, b2, g0, beta0, hbuf);
  k2_spatial<<<dim3(kB*kT), dim3(256), 0, stream>>>(
      hbuf, adj, Theta, g1, beta1);
  probe_frag<<<dim3(1), dim3(64), 0, stream>>>((float*)d_ws);
}

// Round 7
// 490.283 us; speedup vs baseline: 1.3496x; 1.3257x over previous
//
#include <hip/hip_runtime.h>
#include <hip/hip_bf16.h>

typedef unsigned short u16t;

namespace {

constexpr int kB = 16, kD = 64, kN = 200, kT = 48, kH = 8;
constexpr float kEps = 1e-5f;

typedef __attribute__((ext_vector_type(8))) __bf16 bf16x8;
typedef __attribute__((ext_vector_type(4))) float f32x4;
union B8 { int4 i; bf16x8 v; u16t u[8]; };

__device__ __forceinline__ u16t f2bfu(float f) {
  union { __hip_bfloat16 h; u16t u; } c; c.h = __float2bfloat16(f); return c.u;
}

// ---------------- Kernel 1: temporal attention + LN + residual -> h (into d_out), fp32 ----------------
// R6-proven, unchanged.
__global__ __launch_bounds__(256, 2) void k1_temporal(
    const float* __restrict__ x,
    const float* __restrict__ Wq, const float* __restrict__ bq,
    const float* __restrict__ Wk, const float* __restrict__ bk,
    const float* __restrict__ W1, const float* __restrict__ b1,
    const float* __restrict__ W2, const float* __restrict__ b2,
    const float* __restrict__ g0, const float* __restrict__ beta0,
    float* __restrict__ hout)
{
  __shared__ __align__(16) float lds[15616];
  float* xs = lds;              // [64][52]
  float* qs = lds + 3328;       // [64][48]
  float* ks = lds + 6400;       // [64][48]
  float* vs = lds + 9472;       // [64][48]
  float* os = lds + 12544;      // [64][48]

  const int tid = threadIdx.x;
  const int b = blockIdx.x / kN, n = blockIdx.x % kN;

  for (int idx = tid; idx < kD * 6; idx += 256) {
    const int d = idx / 6, j = idx % 6;
    const size_t xi = (size_t)b * (kD*kN*kT) + (size_t)d * (kN*kT) + (size_t)n * kT + j * 8;
    const float4* q = (const float4*)(x + xi);
    const float4 p0 = q[0], p1 = q[1];
    float* dst = xs + d * 52 + 1 + j * 8;
    dst[0]=p0.x; dst[1]=p0.y; dst[2]=p0.z; dst[3]=p0.w;
    dst[4]=p1.x; dst[5]=p1.y; dst[6]=p1.z; dst[7]=p1.w;
  }
  if (tid < 64) { xs[tid*52] = 0.f; xs[tid*52+49] = 0.f; xs[tid*52+50] = 0.f; xs[tid*52+51] = 0.f; }
  __syncthreads();

  {
    const int dq = tid >> 2, t0 = (tid & 3) * 12;
    float aq[12], ak[12], av[12];
    {
      const float vq = bq[dq], vk = bk[dq], vv = b1[dq];
      #pragma unroll
      for (int j = 0; j < 12; ++j) { aq[j] = vq; ak[j] = vk; av[j] = vv; }
    }
    for (int din = 0; din < 64; ++din) {
      union { float4 v4[4]; float f[16]; } X;
      const float4* xr = (const float4*)(xs + din * 52 + t0);
      X.v4[0] = xr[0]; X.v4[1] = xr[1]; X.v4[2] = xr[2]; X.v4[3] = xr[3];
      const size_t wbase = (size_t)dq * 192 + din * 3;
      const float wq0 = Wq[wbase], wq1 = Wq[wbase+1], wq2 = Wq[wbase+2];
      const float wk0 = Wk[wbase], wk1 = Wk[wbase+1], wk2 = Wk[wbase+2];
      const float w1v = W1[(size_t)dq * 64 + din];
      #pragma unroll
      for (int j = 0; j < 12; ++j) {
        aq[j] += X.f[j]*wq0 + X.f[j+1]*wq1 + X.f[j+2]*wq2;
        ak[j] += X.f[j]*wk0 + X.f[j+1]*wk1 + X.f[j+2]*wk2;
        av[j] += X.f[j+1]*w1v;
      }
    }
    float* qd = qs + dq*48 + t0;
    float* kd = ks + dq*48 + t0;
    float* vd = vs + dq*48 + t0;
    #pragma unroll
    for (int j = 0; j < 12; ++j) { qd[j] = aq[j]; kd[j] = ak[j]; vd[j] = av[j]; }
  }
  __syncthreads();

  for (int pair = tid; pair < kH * kT; pair += 256) {
    const int hh = pair / kT, t = pair % kT;
    const int rb = hh * 8;
    float qv[8];
    #pragma unroll
    for (int dk = 0; dk < 8; ++dk) qv[dk] = qs[(rb+dk)*48 + t];
    float sc[48];
    #pragma unroll
    for (int s = 0; s < 48; ++s) sc[s] = 0.f;
    #pragma unroll
    for (int dk = 0; dk < 8; ++dk) {
      const float4* kr = (const float4*)(ks + (rb+dk)*48);
      const float q = qv[dk];
      #pragma unroll
      for (int s4 = 0; s4 < 12; ++s4) {
        const float4 k4 = kr[s4];
        sc[s4*4+0] += q*k4.x; sc[s4*4+1] += q*k4.y;
        sc[s4*4+2] += q*k4.z; sc[s4*4+3] += q*k4.w;
      }
    }
    float mx = -3.4e38f;
    #pragma unroll
    for (int s = 0; s < 48; ++s) { sc[s] *= 0.35355339059327373f; mx = fmaxf(mx, sc[s]); }
    float esum = 0.f;
    #pragma unroll
    for (int s = 0; s < 48; ++s) { sc[s] = __expf(fminf(sc[s] - mx, 0.f)); esum += sc[s]; }
    const float inv = 1.f / esum;
    #pragma unroll
    for (int dk = 0; dk < 8; ++dk) {
      const float4* vr = (const float4*)(vs + (rb+dk)*48);
      float a = 0.f;
      #pragma unroll
      for (int s4 = 0; s4 < 12; ++s4) {
        const float4 v4 = vr[s4];
        a += sc[s4*4+0]*v4.x + sc[s4*4+1]*v4.y + sc[s4*4+2]*v4.z + sc[s4*4+3]*v4.w;
      }
      os[(rb+dk)*48 + t] = a * inv;
    }
  }
  __syncthreads();

  {
    const int dq = tid >> 2, t0 = (tid & 3) * 12;
    float ao[12];
    const float b2v = b2[dq];
    #pragma unroll
    for (int j = 0; j < 12; ++j) ao[j] = b2v;
    for (int din = 0; din < 64; ++din) {
      union { float4 v4[3]; float f[12]; } O;
      const float4* orow = (const float4*)(os + din*48 + t0);
      O.v4[0] = orow[0]; O.v4[1] = orow[1]; O.v4[2] = orow[2];
      const float w = W2[(size_t)dq * 64 + din];
      #pragma unroll
      for (int j = 0; j < 12; ++j) ao[j] += O.f[j] * w;
    }
    float* td = qs + dq*48 + t0;
    #pragma unroll
    for (int j = 0; j < 12; ++j) td[j] = ao[j];
  }
  __syncthreads();

  float* redm = vs;         // [48][4]
  float* redv = vs + 192;   // [48][4]
  float* mrs  = vs + 384;   // [48]
  float* rrs  = vs + 432;   // [48]
  if (tid < 192) {
    const int t = tid >> 2, grp = tid & 3;
    float sm = 0.f, sq = 0.f;
    #pragma unroll
    for (int i = 0; i < 16; ++i) {
      const float v = qs[(grp*16+i)*48 + t];
      sm += v; sq += v*v;
    }
    redm[t*4+grp] = sm; redv[t*4+grp] = sq;
  }
  __syncthreads();
  if (tid < 48) {
    const int t = tid;
    const float sm = redm[t*4] + redm[t*4+1] + redm[t*4+2] + redm[t*4+3];
    const float sq = redv[t*4] + redv[t*4+1] + redv[t*4+2] + redv[t*4+3];
    const float mean = sm * (1.f/64.f);
    const float var = sq * (1.f/64.f) - mean*mean;
    mrs[t] = mean; rrs[t] = rsqrtf(fmaxf(var, 0.f) + kEps);
  }
  __syncthreads();
  if (tid < 192) {
    const int t = tid >> 2, grp = tid & 3;
    const float mean = mrs[t], rs = rrs[t];
    const size_t base = (((size_t)b*kN + n)*kT + t)*kD;
    #pragma unroll
    for (int i = 0; i < 16; ++i) {
      const int d = grp*16 + i;
      const float tout = qs[d*48 + t];
      const float xv = xs[d*52 + t + 1];
      hout[base + d] = xv + (tout - mean)*rs*g0[d] + beta0[d];
    }
  }
}

// ---------------- Kernel 2: spatial GCN via MFMA (fp32 I/O, bf16 GEMM operands), in-place ----------------
// One block per (b,t). Fragment layout hardware-verified by R6 probe (spin=0 path).
__global__ __launch_bounds__(256, 2) void k2_spatial_mfma(
    float* __restrict__ hio, const float* __restrict__ adj,
    const float* __restrict__ Theta, const float* __restrict__ g1,
    const float* __restrict__ beta1)
{
  // elem(n,d) of Hs at n*64 + ((d/8 + n)&7)*8 + d%8 ; rows 200..207 all-zero
  __shared__ __align__(16) u16t Hs[208*64];
  // elem(d,m) of HTs at d*208 + ((m/8 + d)%26)*8 + m%8 ; hole granule (25+d)%26 zeroed
  __shared__ __align__(16) u16t HTs[64*208];
  // elem(r,m) of Wb at r*224 + ((m/8 + r)%28)*8 + m%8 ; cols m>=200 stay zero
  __shared__ __align__(16) u16t Wb[16*224];
  // elem(r,d) of A2 at r*64 + ((d/8 + r)&7)*8 + d%8
  __shared__ __align__(16) u16t A2[16*64];
  __shared__ float rmax[4][16], rsum[4][16], lnS[4][16], lnQ[4][16];

  const int tid = threadIdx.x;
  const int b = blockIdx.x / kT, t = blockIdx.x % kT;
  const int wv = tid >> 6, lane = tid & 63;
  const int c15 = lane & 15, quad = lane >> 4;
  const int myf = wv*16 + c15;                       // this lane's output feature

  const float g1f = g1[myf], be1f = beta1[myf];

  // Theta B-fragment (rb-invariant): Theta[myf][k], k = ksp*32 + quad*8 + j
  B8 bth[2];
  #pragma unroll
  for (int ksp = 0; ksp < 2; ++ksp) {
    const float* tp = Theta + (size_t)myf*64 + ksp*32 + quad*8;
    const float4 a = *(const float4*)tp, c = *(const float4*)(tp + 4);
    bth[ksp].u[0]=f2bfu(a.x); bth[ksp].u[1]=f2bfu(a.y);
    bth[ksp].u[2]=f2bfu(a.z); bth[ksp].u[3]=f2bfu(a.w);
    bth[ksp].u[4]=f2bfu(c.x); bth[ksp].u[5]=f2bfu(c.y);
    bth[ksp].u[6]=f2bfu(c.z); bth[ksp].u[7]=f2bfu(c.w);
  }

  // ---- stage h(b,:,t,:) fp32 -> bf16 into Hs + HTs; zero pads ----
  for (int idx = tid; idx < kN*8; idx += 256) {
    const int n = idx >> 3, j = idx & 7;
    const float* src = hio + (((size_t)b*kN + n)*kT + t)*kD + j*8;
    const float4 p0 = *(const float4*)src, p1 = *(const float4*)(src + 4);
    B8 p;
    p.u[0]=f2bfu(p0.x); p.u[1]=f2bfu(p0.y); p.u[2]=f2bfu(p0.z); p.u[3]=f2bfu(p0.w);
    p.u[4]=f2bfu(p1.x); p.u[5]=f2bfu(p1.y); p.u[6]=f2bfu(p1.z); p.u[7]=f2bfu(p1.w);
    *(int4*)(Hs + n*64 + (((j + n) & 7) << 3)) = p.i;
    #pragma unroll
    for (int e = 0; e < 8; ++e) {
      const int d = j*8 + e;
      HTs[d*208 + (((n >> 3) + d) % 26)*8 + (n & 7)] = p.u[e];
    }
  }
  if (tid < 64) {            // Hs rows 200..207 := 0
    *(int4*)(Hs + (200 + (tid >> 3))*64 + ((tid & 7) << 3)) = make_int4(0,0,0,0);
  } else if (tid < 128) {    // HTs hole granule per row d := 0
    const int d = tid - 64;
    *(int4*)(HTs + d*208 + (((25 + d) % 26) << 3)) = make_int4(0,0,0,0);
  }
  for (int idx = tid; idx < (16*224)/8; idx += 256)
    *(int4*)(Wb + idx*8) = make_int4(0,0,0,0);
  __syncthreads();

  for (int rb = 0; rb < 13; ++rb) {
    const int n0 = rb * 16;

    // ---- Phase A: scores S[n][m] = (h_n . h_m)/8 ----
    B8 afr[2];
    #pragma unroll
    for (int ksp = 0; ksp < 2; ++ksp) {
      const int row = n0 + c15;
      afr[ksp].i = *(const int4*)(Hs + row*64 + (((ksp*4 + quad + row) & 7) << 3));
    }
    f32x4 cs[3];
    #pragma unroll
    for (int i = 0; i < 3; ++i) {
      const int mt = wv + 4*i;
      f32x4 acc = {0.f, 0.f, 0.f, 0.f};
      #pragma unroll
      for (int ksp = 0; ksp < 2; ++ksp) {
        const int row = mt*16 + c15;
        B8 bfr; bfr.i = *(const int4*)(Hs + row*64 + (((ksp*4 + quad + row) & 7) << 3));
        acc = __builtin_amdgcn_mfma_f32_16x16x32_bf16(afr[ksp].v, bfr.v, acc, 0, 0, 0);
      }
      cs[i] = acc;
    }
    const bool has4 = (wv == 0);
    f32x4 cs3 = {0.f, 0.f, 0.f, 0.f};
    if (has4) {
      #pragma unroll
      for (int ksp = 0; ksp < 2; ++ksp) {
        const int row = 192 + c15;                  // rows 200..207 zero-padded
        B8 bfr; bfr.i = *(const int4*)(Hs + row*64 + (((ksp*4 + quad + row) & 7) << 3));
        cs3 = __builtin_amdgcn_mfma_f32_16x16x32_bf16(afr[ksp].v, bfr.v, cs3, 0, 0, 0);
      }
    }
    float mxr[4];
    #pragma unroll
    for (int r = 0; r < 4; ++r) {
      cs[0][r] *= 0.125f; cs[1][r] *= 0.125f; cs[2][r] *= 0.125f; cs3[r] *= 0.125f;
      float m = fmaxf(fmaxf(cs[0][r], cs[1][r]), cs[2][r]);
      if (has4 && c15 < 8) m = fmaxf(m, cs3[r]);
      mxr[r] = m;
    }
    #pragma unroll
    for (int off = 1; off <= 8; off <<= 1)
      #pragma unroll
      for (int r = 0; r < 4; ++r) mxr[r] = fmaxf(mxr[r], __shfl_xor(mxr[r], off, 64));
    if (c15 == 0) {
      #pragma unroll
      for (int r = 0; r < 4; ++r) rmax[wv][quad*4 + r] = mxr[r];
    }
    __syncthreads();
    float mx[4], sm[4];
    #pragma unroll
    for (int r = 0; r < 4; ++r) {
      const int rr = quad*4 + r;
      mx[r] = fmaxf(fmaxf(rmax[0][rr], rmax[1][rr]), fmaxf(rmax[2][rr], rmax[3][rr]));
      cs[0][r] = __expf(fminf(cs[0][r] - mx[r], 0.f));
      cs[1][r] = __expf(fminf(cs[1][r] - mx[r], 0.f));
      cs[2][r] = __expf(fminf(cs[2][r] - mx[r], 0.f));
      cs3[r]   = (has4 && c15 < 8) ? __expf(fminf(cs3[r] - mx[r], 0.f)) : 0.f;
      sm[r] = cs[0][r] + cs[1][r] + cs[2][r] + cs3[r];
    }
    #pragma unroll
    for (int off = 1; off <= 8; off <<= 1)
      #pragma unroll
      for (int r = 0; r < 4; ++r) sm[r] += __shfl_xor(sm[r], off, 64);
    if (c15 == 0) {
      #pragma unroll
      for (int r = 0; r < 4; ++r) rsum[wv][quad*4 + r] = sm[r];
    }
    __syncthreads();
    #pragma unroll
    for (int r = 0; r < 4; ++r) {
      const int rr = quad*4 + r;
      const float tot = rsum[0][rr] + rsum[1][rr] + rsum[2][rr] + rsum[3][rr];
      const float inv = 0.125f / fmaxf(tot, 1e-20f);         // softmax / sqrt(D)
      const int n = n0 + rr;
      const bool vrow = (n < kN);
      const int na = vrow ? n : (kN - 1);
      #pragma unroll
      for (int i = 0; i < 3; ++i) {
        const int m = (wv + 4*i)*16 + c15;
        const float w = vrow ? cs[i][r] * inv * adj[(size_t)na*kN + m] : 0.f;
        Wb[rr*224 + (((m >> 3) + rr) % 28)*8 + (m & 7)] = f2bfu(w);
      }
      if (has4 && c15 < 8) {
        const int m = 192 + c15;
        const float w = vrow ? cs3[r] * inv * adj[(size_t)na*kN + m] : 0.f;
        Wb[rr*224 + (((m >> 3) + rr) % 28)*8 + (m & 7)] = f2bfu(w);
      }
    }
    __syncthreads();   // Wb complete

    // ---- Phase B: agg^T[d][rr] = sum_m h[m][d] * w[rr][m]; wave handles d-tile wv ----
    f32x4 ag = {0.f, 0.f, 0.f, 0.f};
    const int dA = wv*16 + c15;
    #pragma unroll
    for (int ksp = 0; ksp < 7; ++ksp) {
      B8 a;
      if (ksp == 6) {
        if (quad == 0) a.i = *(const int4*)(HTs + dA*208 + ((24 + dA) % 26)*8);
        else a.i = make_int4(0, 0, 0, 0);                    // m >= 200 -> 0
      } else {
        a.i = *(const int4*)(HTs + dA*208 + ((ksp*4 + quad + dA) % 26)*8);
      }
      B8 bw; bw.i = *(const int4*)(Wb + c15*224 + ((ksp*4 + quad + c15) % 28)*8);
      ag = __builtin_amdgcn_mfma_f32_16x16x32_bf16(a.v, bw.v, ag, 0, 0, 0);
    }
    {
      const int dbase = wv*16 + quad*4;
      #pragma unroll
      for (int r = 0; r < 4; ++r) {
        const int d = dbase + r;
        A2[c15*64 + (((d >> 3) + c15) & 7)*8 + (d & 7)] = f2bfu(ag[r]);
      }
    }
    __syncthreads();   // A2 complete

    // ---- Phase C: out = relu(A2 @ Theta^T); LN + residual ----
    f32x4 o = {0.f, 0.f, 0.f, 0.f};
    #pragma unroll
    for (int ksp = 0; ksp < 2; ++ksp) {
      B8 a; a.i = *(const int4*)(A2 + c15*64 + (((ksp*4 + quad + c15) & 7) << 3));
      o = __builtin_amdgcn_mfma_f32_16x16x32_bf16(a.v, bth[ksp].v, o, 0, 0, 0);
    }
    float vr[4], ps[4], pq[4];
    #pragma unroll
    for (int r = 0; r < 4; ++r) {
      vr[r] = fmaxf(o[r], 0.f);
      ps[r] = vr[r]; pq[r] = vr[r]*vr[r];
    }
    #pragma unroll
    for (int off = 1; off <= 8; off <<= 1)
      #pragma unroll
      for (int r = 0; r < 4; ++r) {
        ps[r] += __shfl_xor(ps[r], off, 64);
        pq[r] += __shfl_xor(pq[r], off, 64);
      }
    if (c15 == 0) {
      #pragma unroll
      for (int r = 0; r < 4; ++r) { lnS[wv][quad*4+r] = ps[r]; lnQ[wv][quad*4+r] = pq[r]; }
    }
    __syncthreads();   // LN partials complete
    #pragma unroll
    for (int r = 0; r < 4; ++r) {
      const int rr = quad*4 + r, n = n0 + rr;
      const float S = lnS[0][rr] + lnS[1][rr] + lnS[2][rr] + lnS[3][rr];
      const float Q = lnQ[0][rr] + lnQ[1][rr] + lnQ[2][rr] + lnQ[3][rr];
      const float mean = S * (1.f/64.f);
      const float var = Q * (1.f/64.f) - mean*mean;
      const float rs = rsqrtf(fmaxf(var, 0.f) + kEps);
      if (n < kN) {
        const float sout = (vr[r] - mean)*rs*g1f + be1f;
        const size_t oi = (((size_t)b*kN + n)*kT + t)*kD + myf;
        hio[oi] = hio[oi] + sout;    // fp32 residual re-read (L2-warm)
      }
    }
  }
}

} // namespace

extern "C" void kernel_launch(void* const* d_in, const int* in_sizes, int n_in,
                              void* d_out, int out_size, void* d_ws, size_t ws_size,
                              hipStream_t stream) {
  const float* x     = (const float*)d_in[0];
  const float* adj   = (const float*)d_in[1];
  const float* Wq    = (const float*)d_in[2];
  const float* bq    = (const float*)d_in[3];
  const float* Wk    = (const float*)d_in[4];
  const float* bk    = (const float*)d_in[5];
  const float* W1    = (const float*)d_in[6];
  const float* b1    = (const float*)d_in[7];
  const float* W2    = (const float*)d_in[8];
  const float* b2    = (const float*)d_in[9];
  const float* Theta = (const float*)d_in[10];
  const float* g0    = (const float*)d_in[11];
  const float* beta0 = (const float*)d_in[12];
  const float* g1    = (const float*)d_in[13];
  const float* beta1 = (const float*)d_in[14];

  float* hbuf = (float*)d_out;   // h staged in-place through d_out (fp32)

  k1_temporal<<<dim3(kB*kN), dim3(256), 0, stream>>>(
      x, Wq, bq, Wk, bk, W1, b1, W2, b2, g0, beta0, hbuf);
  k2_spatial_mfma<<<dim3(kB*kT), dim3(256), 0, stream>>>(
      hbuf, adj, Theta, g1, beta1);
}

// Round 8
// 393.338 us; speedup vs baseline: 1.6822x; 1.2465x over previous
//
#include <hip/hip_runtime.h>
#include <hip/hip_bf16.h>

typedef unsigned short u16t;

namespace {

constexpr int kB = 16, kD = 64, kN = 200, kT = 48, kH = 8;
constexpr float kEps = 1e-5f;

typedef __attribute__((ext_vector_type(8))) __bf16 bf16x8;
typedef __attribute__((ext_vector_type(4))) float f32x4;
union B8 { int4 i; bf16x8 v; u16t u[8]; };

__device__ __forceinline__ u16t f2bfu(float f) {
  union { __hip_bfloat16 h; u16t u; } c; c.h = __float2bfloat16(f); return c.u;
}

// ---------------- Kernel 1: temporal attention via MFMA convs/projs + VALU softmax ----------------
// One block per (b,n). GEMMs (conv-q, conv-k, v-proj, W2-proj) on MFMA with bf16 operands;
// softmax + LN in fp32. Fragment layout HW-verified (R6 probe).
__global__ __launch_bounds__(256, 2) void k1_temporal(
    const float* __restrict__ x,
    const float* __restrict__ Wq, const float* __restrict__ bq,
    const float* __restrict__ Wk, const float* __restrict__ bk,
    const float* __restrict__ W1, const float* __restrict__ b1,
    const float* __restrict__ W2, const float* __restrict__ b2,
    const float* __restrict__ g0, const float* __restrict__ beta0,
    float* __restrict__ hout)
{
  // fp32: xs [64][52] (residual), qs/ks/vs [64][48]
  __shared__ __align__(16) float lds_f[3328 + 3*3072];
  // bf16: XT [50][64] rot-swizzled (row r = t+1; rows 0,49 zero), osT [48][64] rot-swizzled
  __shared__ __align__(16) u16t lds_h[3200 + 3072];
  float* xs = lds_f;
  float* qs = lds_f + 3328;
  float* ks = lds_f + 6400;
  float* vs = lds_f + 9472;
  u16t* XT  = lds_h;            // elem(r,d) at r*64 + ((d/8 + r)&7)*8 + d%8
  u16t* osT = lds_h + 3200;     // elem(t,e) at t*64 + ((e/8 + t)&7)*8 + e%8

  const int tid = threadIdx.x;
  const int b = blockIdx.x / kN, n = blockIdx.x % kN;
  const int wv = tid >> 6, lane = tid & 63;
  const int c15 = lane & 15, quad = lane >> 4;

  // ---- stage x[b,:,n,:] -> xs (fp32) + XT (bf16 transposed, swizzled) ----
  for (int idx = tid; idx < kD * 6; idx += 256) {
    const int d = idx / 6, j = idx % 6;
    const size_t xi = (size_t)b * (kD*kN*kT) + (size_t)d * (kN*kT) + (size_t)n * kT + j * 8;
    const float4* q = (const float4*)(x + xi);
    const float4 p0 = q[0], p1 = q[1];
    float f[8];
    f[0]=p0.x; f[1]=p0.y; f[2]=p0.z; f[3]=p0.w; f[4]=p1.x; f[5]=p1.y; f[6]=p1.z; f[7]=p1.w;
    float* dst = xs + d * 52 + 1 + j * 8;
    #pragma unroll
    for (int e = 0; e < 8; ++e) dst[e] = f[e];
    #pragma unroll
    for (int e = 0; e < 8; ++e) {
      const int r = j*8 + e + 1;            // row = t+1
      XT[r*64 + (((d >> 3) + r) & 7)*8 + (d & 7)] = f2bfu(f[e]);
    }
  }
  if (tid < 16) {                            // XT rows 0 and 49 := 0
    const int rr = (tid >> 3) ? 49 : 0, g = tid & 7;
    *(int4*)(XT + rr*64 + g*8) = make_int4(0,0,0,0);
  }
  __syncthreads();

  // ---- QKV via MFMA: wave wv owns output-channel tile wv ----
  {
    const int dqr = wv*16 + c15;             // A-operand M row
    B8 aq[6], ak[6], av2[2];
    #pragma unroll
    for (int tap = 0; tap < 3; ++tap)
      #pragma unroll
      for (int ksp = 0; ksp < 2; ++ksp) {
        const float* wqp = Wq + (size_t)dqr*192 + tap;
        const float* wkp = Wk + (size_t)dqr*192 + tap;
        const int kb = ksp*32 + quad*8;
        #pragma unroll
        for (int j = 0; j < 8; ++j) {
          aq[tap*2+ksp].u[j] = f2bfu(wqp[(kb + j)*3]);
          ak[tap*2+ksp].u[j] = f2bfu(wkp[(kb + j)*3]);
        }
      }
    #pragma unroll
    for (int ksp = 0; ksp < 2; ++ksp) {
      const float* w1p = W1 + (size_t)dqr*64 + ksp*32 + quad*8;
      const float4 a = *(const float4*)w1p, c = *(const float4*)(w1p + 4);
      av2[ksp].u[0]=f2bfu(a.x); av2[ksp].u[1]=f2bfu(a.y); av2[ksp].u[2]=f2bfu(a.z); av2[ksp].u[3]=f2bfu(a.w);
      av2[ksp].u[4]=f2bfu(c.x); av2[ksp].u[5]=f2bfu(c.y); av2[ksp].u[6]=f2bfu(c.z); av2[ksp].u[7]=f2bfu(c.w);
    }
    float bqv[4], bkv[4], b1v[4];
    #pragma unroll
    for (int r = 0; r < 4; ++r) {
      const int row = wv*16 + quad*4 + r;
      bqv[r] = bq[row]; bkv[r] = bk[row]; b1v[r] = b1[row];
    }

    for (int i = 0; i < 3; ++i) {
      const int t0 = i * 16;
      B8 bf[3][2];
      #pragma unroll
      for (int tap = 0; tap < 3; ++tap)
        #pragma unroll
        for (int ksp = 0; ksp < 2; ++ksp) {
          const int r = t0 + c15 + tap;      // XT row = t + tap
          bf[tap][ksp].i = *(const int4*)(XT + r*64 + (((ksp*4 + quad) + r) & 7)*8);
        }
      f32x4 accq = {0.f,0.f,0.f,0.f}, acck = {0.f,0.f,0.f,0.f}, accv = {0.f,0.f,0.f,0.f};
      #pragma unroll
      for (int tap = 0; tap < 3; ++tap)
        #pragma unroll
        for (int ksp = 0; ksp < 2; ++ksp) {
          accq = __builtin_amdgcn_mfma_f32_16x16x32_bf16(aq[tap*2+ksp].v, bf[tap][ksp].v, accq, 0, 0, 0);
          acck = __builtin_amdgcn_mfma_f32_16x16x32_bf16(ak[tap*2+ksp].v, bf[tap][ksp].v, acck, 0, 0, 0);
        }
      #pragma unroll
      for (int ksp = 0; ksp < 2; ++ksp)      // v uses tap=1 B-frag (row t+1 = X col t)
        accv = __builtin_amdgcn_mfma_f32_16x16x32_bf16(av2[ksp].v, bf[1][ksp].v, accv, 0, 0, 0);
      #pragma unroll
      for (int r = 0; r < 4; ++r) {
        const int row = wv*16 + quad*4 + r, col = t0 + c15;
        qs[row*48 + col] = accq[r] + bqv[r];
        ks[row*48 + col] = acck[r] + bkv[r];
        vs[row*48 + col] = accv[r] + b1v[r];
      }
    }
  }
  __syncthreads();

  // ---- attention per (h,t): scores, softmax, P@V -> osT (bf16, swizzled) ----
  for (int pair = tid; pair < kH * kT; pair += 256) {
    const int hh = pair / kT, t = pair % kT;
    const int rb = hh * 8;
    float qv[8];
    #pragma unroll
    for (int dk = 0; dk < 8; ++dk) qv[dk] = qs[(rb+dk)*48 + t];
    float sc[48];
    #pragma unroll
    for (int s = 0; s < 48; ++s) sc[s] = 0.f;
    #pragma unroll
    for (int dk = 0; dk < 8; ++dk) {
      const float4* kr = (const float4*)(ks + (rb+dk)*48);
      const float q = qv[dk];
      #pragma unroll
      for (int s4 = 0; s4 < 12; ++s4) {
        const float4 k4 = kr[s4];
        sc[s4*4+0] += q*k4.x; sc[s4*4+1] += q*k4.y;
        sc[s4*4+2] += q*k4.z; sc[s4*4+3] += q*k4.w;
      }
    }
    float mx = -3.4e38f;
    #pragma unroll
    for (int s = 0; s < 48; ++s) { sc[s] *= 0.35355339059327373f; mx = fmaxf(mx, sc[s]); }
    float esum = 0.f;
    #pragma unroll
    for (int s = 0; s < 48; ++s) { sc[s] = __expf(fminf(sc[s] - mx, 0.f)); esum += sc[s]; }
    const float inv = 1.f / esum;
    B8 pk;
    #pragma unroll
    for (int dk = 0; dk < 8; ++dk) {
      const float4* vr = (const float4*)(vs + (rb+dk)*48);
      float a = 0.f;
      #pragma unroll
      for (int s4 = 0; s4 < 12; ++s4) {
        const float4 v4 = vr[s4];
        a += sc[s4*4+0]*v4.x + sc[s4*4+1]*v4.y + sc[s4*4+2]*v4.z + sc[s4*4+3]*v4.w;
      }
      pk.u[dk] = f2bfu(a * inv);
    }
    *(int4*)(osT + t*64 + ((hh + t) & 7)*8) = pk.i;   // e = rb..rb+7, e>>3 = hh
  }
  __syncthreads();

  // ---- W2 projection via MFMA -> qs (tout) ----
  {
    const int dqr = wv*16 + c15;
    B8 a2[2];
    #pragma unroll
    for (int ksp = 0; ksp < 2; ++ksp) {
      const float* w2p = W2 + (size_t)dqr*64 + ksp*32 + quad*8;
      const float4 a = *(const float4*)w2p, c = *(const float4*)(w2p + 4);
      a2[ksp].u[0]=f2bfu(a.x); a2[ksp].u[1]=f2bfu(a.y); a2[ksp].u[2]=f2bfu(a.z); a2[ksp].u[3]=f2bfu(a.w);
      a2[ksp].u[4]=f2bfu(c.x); a2[ksp].u[5]=f2bfu(c.y); a2[ksp].u[6]=f2bfu(c.z); a2[ksp].u[7]=f2bfu(c.w);
    }
    float b2v[4];
    #pragma unroll
    for (int r = 0; r < 4; ++r) b2v[r] = b2[wv*16 + quad*4 + r];
    for (int i = 0; i < 3; ++i) {
      const int t0 = i * 16;
      f32x4 acc = {0.f,0.f,0.f,0.f};
      #pragma unroll
      for (int ksp = 0; ksp < 2; ++ksp) {
        const int r = t0 + c15;
        B8 bo; bo.i = *(const int4*)(osT + r*64 + (((ksp*4 + quad) + r) & 7)*8);
        acc = __builtin_amdgcn_mfma_f32_16x16x32_bf16(a2[ksp].v, bo.v, acc, 0, 0, 0);
      }
      #pragma unroll
      for (int r = 0; r < 4; ++r)
        qs[(wv*16 + quad*4 + r)*48 + t0 + c15] = acc[r] + b2v[r];
    }
  }
  __syncthreads();

  // ---- LayerNorm over D + residual, write h ----
  float* redm = vs;         // [48][4]
  float* redv = vs + 192;   // [48][4]
  float* mrs  = vs + 384;   // [48]
  float* rrs  = vs + 432;   // [48]
  if (tid < 192) {
    const int t = tid >> 2, grp = tid & 3;
    float sm = 0.f, sq = 0.f;
    #pragma unroll
    for (int i = 0; i < 16; ++i) {
      const float v = qs[(grp*16+i)*48 + t];
      sm += v; sq += v*v;
    }
    redm[t*4+grp] = sm; redv[t*4+grp] = sq;
  }
  __syncthreads();
  if (tid < 48) {
    const int t = tid;
    const float sm = redm[t*4] + redm[t*4+1] + redm[t*4+2] + redm[t*4+3];
    const float sq = redv[t*4] + redv[t*4+1] + redv[t*4+2] + redv[t*4+3];
    const float mean = sm * (1.f/64.f);
    const float var = sq * (1.f/64.f) - mean*mean;
    mrs[t] = mean; rrs[t] = rsqrtf(fmaxf(var, 0.f) + kEps);
  }
  __syncthreads();
  if (tid < 192) {
    const int t = tid >> 2, grp = tid & 3;
    const float mean = mrs[t], rs = rrs[t];
    const size_t base = (((size_t)b*kN + n)*kT + t)*kD;
    #pragma unroll
    for (int i = 0; i < 16; ++i) {
      const int d = grp*16 + i;
      const float tout = qs[d*48 + t];
      const float xv = xs[d*52 + t + 1];
      hout[base + d] = xv + (tout - mean)*rs*g0[d] + beta0[d];
    }
  }
}

// ---------------- Kernel 2: spatial GCN via MFMA (R7-proven), in-place on d_out ----------------
__global__ __launch_bounds__(256, 2) void k2_spatial_mfma(
    float* __restrict__ hio, const float* __restrict__ adj,
    const float* __restrict__ Theta, const float* __restrict__ g1,
    const float* __restrict__ beta1)
{
  __shared__ __align__(16) u16t Hs[208*64];
  __shared__ __align__(16) u16t HTs[64*208];
  __shared__ __align__(16) u16t Wb[16*224];
  __shared__ __align__(16) u16t A2[16*64];
  __shared__ float rmax[4][16], rsum[4][16], lnS[4][16], lnQ[4][16];

  const int tid = threadIdx.x;
  const int b = blockIdx.x / kT, t = blockIdx.x % kT;
  const int wv = tid >> 6, lane = tid & 63;
  const int c15 = lane & 15, quad = lane >> 4;
  const int myf = wv*16 + c15;

  const float g1f = g1[myf], be1f = beta1[myf];

  B8 bth[2];
  #pragma unroll
  for (int ksp = 0; ksp < 2; ++ksp) {
    const float* tp = Theta + (size_t)myf*64 + ksp*32 + quad*8;
    const float4 a = *(const float4*)tp, c = *(const float4*)(tp + 4);
    bth[ksp].u[0]=f2bfu(a.x); bth[ksp].u[1]=f2bfu(a.y);
    bth[ksp].u[2]=f2bfu(a.z); bth[ksp].u[3]=f2bfu(a.w);
    bth[ksp].u[4]=f2bfu(c.x); bth[ksp].u[5]=f2bfu(c.y);
    bth[ksp].u[6]=f2bfu(c.z); bth[ksp].u[7]=f2bfu(c.w);
  }

  for (int idx = tid; idx < kN*8; idx += 256) {
    const int n = idx >> 3, j = idx & 7;
    const float* src = hio + (((size_t)b*kN + n)*kT + t)*kD + j*8;
    const float4 p0 = *(const float4*)src, p1 = *(const float4*)(src + 4);
    B8 p;
    p.u[0]=f2bfu(p0.x); p.u[1]=f2bfu(p0.y); p.u[2]=f2bfu(p0.z); p.u[3]=f2bfu(p0.w);
    p.u[4]=f2bfu(p1.x); p.u[5]=f2bfu(p1.y); p.u[6]=f2bfu(p1.z); p.u[7]=f2bfu(p1.w);
    *(int4*)(Hs + n*64 + (((j + n) & 7) << 3)) = p.i;
    #pragma unroll
    for (int e = 0; e < 8; ++e) {
      const int d = j*8 + e;
      HTs[d*208 + (((n >> 3) + d) % 26)*8 + (n & 7)] = p.u[e];
    }
  }
  if (tid < 64) {
    *(int4*)(Hs + (200 + (tid >> 3))*64 + ((tid & 7) << 3)) = make_int4(0,0,0,0);
  } else if (tid < 128) {
    const int d = tid - 64;
    *(int4*)(HTs + d*208 + (((25 + d) % 26) << 3)) = make_int4(0,0,0,0);
  }
  for (int idx = tid; idx < (16*224)/8; idx += 256)
    *(int4*)(Wb + idx*8) = make_int4(0,0,0,0);
  __syncthreads();

  for (int rb = 0; rb < 13; ++rb) {
    const int n0 = rb * 16;

    B8 afr[2];
    #pragma unroll
    for (int ksp = 0; ksp < 2; ++ksp) {
      const int row = n0 + c15;
      afr[ksp].i = *(const int4*)(Hs + row*64 + (((ksp*4 + quad + row) & 7) << 3));
    }
    f32x4 cs[3];
    #pragma unroll
    for (int i = 0; i < 3; ++i) {
      const int mt = wv + 4*i;
      f32x4 acc = {0.f, 0.f, 0.f, 0.f};
      #pragma unroll
      for (int ksp = 0; ksp < 2; ++ksp) {
        const int row = mt*16 + c15;
        B8 bfr; bfr.i = *(const int4*)(Hs + row*64 + (((ksp*4 + quad + row) & 7) << 3));
        acc = __builtin_amdgcn_mfma_f32_16x16x32_bf16(afr[ksp].v, bfr.v, acc, 0, 0, 0);
      }
      cs[i] = acc;
    }
    const bool has4 = (wv == 0);
    f32x4 cs3 = {0.f, 0.f, 0.f, 0.f};
    if (has4) {
      #pragma unroll
      for (int ksp = 0; ksp < 2; ++ksp) {
        const int row = 192 + c15;
        B8 bfr; bfr.i = *(const int4*)(Hs + row*64 + (((ksp*4 + quad + row) & 7) << 3));
        cs3 = __builtin_amdgcn_mfma_f32_16x16x32_bf16(afr[ksp].v, bfr.v, cs3, 0, 0, 0);
      }
    }
    float mxr[4];
    #pragma unroll
    for (int r = 0; r < 4; ++r) {
      cs[0][r] *= 0.125f; cs[1][r] *= 0.125f; cs[2][r] *= 0.125f; cs3[r] *= 0.125f;
      float m = fmaxf(fmaxf(cs[0][r], cs[1][r]), cs[2][r]);
      if (has4 && c15 < 8) m = fmaxf(m, cs3[r]);
      mxr[r] = m;
    }
    #pragma unroll
    for (int off = 1; off <= 8; off <<= 1)
      #pragma unroll
      for (int r = 0; r < 4; ++r) mxr[r] = fmaxf(mxr[r], __shfl_xor(mxr[r], off, 64));
    if (c15 == 0) {
      #pragma unroll
      for (int r = 0; r < 4; ++r) rmax[wv][quad*4 + r] = mxr[r];
    }
    __syncthreads();
    float mx[4], sm[4];
    #pragma unroll
    for (int r = 0; r < 4; ++r) {
      const int rr = quad*4 + r;
      mx[r] = fmaxf(fmaxf(rmax[0][rr], rmax[1][rr]), fmaxf(rmax[2][rr], rmax[3][rr]));
      cs[0][r] = __expf(fminf(cs[0][r] - mx[r], 0.f));
      cs[1][r] = __expf(fminf(cs[1][r] - mx[r], 0.f));
      cs[2][r] = __expf(fminf(cs[2][r] - mx[r], 0.f));
      cs3[r]   = (has4 && c15 < 8) ? __expf(fminf(cs3[r] - mx[r], 0.f)) : 0.f;
      sm[r] = cs[0][r] + cs[1][r] + cs[2][r] + cs3[r];
    }
    #pragma unroll
    for (int off = 1; off <= 8; off <<= 1)
      #pragma unroll
      for (int r = 0; r < 4; ++r) sm[r] += __shfl_xor(sm[r], off, 64);
    if (c15 == 0) {
      #pragma unroll
      for (int r = 0; r < 4; ++r) rsum[wv][quad*4 + r] = sm[r];
    }
    __syncthreads();
    #pragma unroll
    for (int r = 0; r < 4; ++r) {
      const int rr = quad*4 + r;
      const float tot = rsum[0][rr] + rsum[1][rr] + rsum[2][rr] + rsum[3][rr];
      const float inv = 0.125f / fmaxf(tot, 1e-20f);
      const int n = n0 + rr;
      const bool vrow = (n < kN);
      const int na = vrow ? n : (kN - 1);
      #pragma unroll
      for (int i = 0; i < 3; ++i) {
        const int m = (wv + 4*i)*16 + c15;
        const float w = vrow ? cs[i][r] * inv * adj[(size_t)na*kN + m] : 0.f;
        Wb[rr*224 + (((m >> 3) + rr) % 28)*8 + (m & 7)] = f2bfu(w);
      }
      if (has4 && c15 < 8) {
        const int m = 192 + c15;
        const float w = vrow ? cs3[r] * inv * adj[(size_t)na*kN + m] : 0.f;
        Wb[rr*224 + (((m >> 3) + rr) % 28)*8 + (m & 7)] = f2bfu(w);
      }
    }
    __syncthreads();

    f32x4 ag = {0.f, 0.f, 0.f, 0.f};
    const int dA = wv*16 + c15;
    #pragma unroll
    for (int ksp = 0; ksp < 7; ++ksp) {
      B8 a;
      if (ksp == 6) {
        if (quad == 0) a.i = *(const int4*)(HTs + dA*208 + ((24 + dA) % 26)*8);
        else a.i = make_int4(0, 0, 0, 0);
      } else {
        a.i = *(const int4*)(HTs + dA*208 + ((ksp*4 + quad + dA) % 26)*8);
      }
      B8 bw; bw.i = *(const int4*)(Wb + c15*224 + ((ksp*4 + quad + c15) % 28)*8);
      ag = __builtin_amdgcn_mfma_f32_16x16x32_bf16(a.v, bw.v, ag, 0, 0, 0);
    }
    {
      const int dbase = wv*16 + quad*4;
      #pragma unroll
      for (int r = 0; r < 4; ++r) {
        const int d = dbase + r;
        A2[c15*64 + (((d >> 3) + c15) & 7)*8 + (d & 7)] = f2bfu(ag[r]);
      }
    }
    __syncthreads();

    f32x4 o = {0.f, 0.f, 0.f, 0.f};
    #pragma unroll
    for (int ksp = 0; ksp < 2; ++ksp) {
      B8 a; a.i = *(const int4*)(A2 + c15*64 + (((ksp*4 + quad + c15) & 7) << 3));
      o = __builtin_amdgcn_mfma_f32_16x16x32_bf16(a.v, bth[ksp].v, o, 0, 0, 0);
    }
    float vr[4], ps[4], pq[4];
    #pragma unroll
    for (int r = 0; r < 4; ++r) {
      vr[r] = fmaxf(o[r], 0.f);
      ps[r] = vr[r]; pq[r] = vr[r]*vr[r];
    }
    #pragma unroll
    for (int off = 1; off <= 8; off <<= 1)
      #pragma unroll
      for (int r = 0; r < 4; ++r) {
        ps[r] += __shfl_xor(ps[r], off, 64);
        pq[r] += __shfl_xor(pq[r], off, 64);
      }
    if (c15 == 0) {
      #pragma unroll
      for (int r = 0; r < 4; ++r) { lnS[wv][quad*4+r] = ps[r]; lnQ[wv][quad*4+r] = pq[r]; }
    }
    __syncthreads();
    #pragma unroll
    for (int r = 0; r < 4; ++r) {
      const int rr = quad*4 + r, n = n0 + rr;
      const float S = lnS[0][rr] + lnS[1][rr] + lnS[2][rr] + lnS[3][rr];
      const float Q = lnQ[0][rr] + lnQ[1][rr] + lnQ[2][rr] + lnQ[3][rr];
      const float mean = S * (1.f/64.f);
      const float var = Q * (1.f/64.f) - mean*mean;
      const float rs = rsqrtf(fmaxf(var, 0.f) + kEps);
      if (n < kN) {
        const float sout = (vr[r] - mean)*rs*g1f + be1f;
        const size_t oi = (((size_t)b*kN + n)*kT + t)*kD + myf;
        hio[oi] = hio[oi] + sout;
      }
    }
  }
}

} // namespace

extern "C" void kernel_launch(void* const* d_in, const int* in_sizes, int n_in,
                              void* d_out, int out_size, void* d_ws, size_t ws_size,
                              hipStream_t stream) {
  const float* x     = (const float*)d_in[0];
  const float* adj   = (const float*)d_in[1];
  const float* Wq    = (const float*)d_in[2];
  const float* bq    = (const float*)d_in[3];
  const float* Wk    = (const float*)d_in[4];
  const float* bk    = (const float*)d_in[5];
  const float* W1    = (const float*)d_in[6];
  const float* b1    = (const float*)d_in[7];
  const float* W2    = (const float*)d_in[8];
  const float* b2    = (const float*)d_in[9];
  const float* Theta = (const float*)d_in[10];
  const float* g0    = (const float*)d_in[11];
  const float* beta0 = (const float*)d_in[12];
  const float* g1    = (const float*)d_in[13];
  const float* beta1 = (const float*)d_in[14];

  float* hbuf = (float*)d_out;   // h staged in-place through d_out (fp32)

  k1_temporal<<<dim3(kB*kN), dim3(256), 0, stream>>>(
      x, Wq, bq, Wk, bk, W1, b1, W2, b2, g0, beta0, hbuf);
  k2_spatial_mfma<<<dim3(kB*kT), dim3(256), 0, stream>>>(
      hbuf, adj, Theta, g1, beta1);
}